// Round 1
// baseline (19862.628 us; speedup 1.0000x reference)
//
#include <hip/hip_runtime.h>
#include <math.h>

#define IN_CH 256
#define CI_CH 8

// Fallback ping-pong activation buffers (level 0: 4*256*128*128 floats = 64 MiB each)
__device__ float g_buf0[4 * 256 * 128 * 128];
__device__ float g_buf1[4 * 256 * 128 * 128];

// ---------------------------------------------------------------------------
// 3x3 conv (SAME, stride 1) + per-channel scale/bias + ReLU.
// Block: 256 threads. Covers: one n, 32 output channels, 8x16 spatial tile.
// Thread: 4 co x 4-wide pixel strip (16 accumulators).
// ---------------------------------------------------------------------------
__global__ __launch_bounds__(256) void conv3x3_bn_relu(
    const float* __restrict__ in, const float* __restrict__ wgt,
    const float* __restrict__ scale, const float* __restrict__ bias,
    float* __restrict__ out, int H, int W, int tilesX)
{
    __shared__ float in_s[CI_CH][10][20];      // 8 ci x (8+2) x (16+2), stride 20 for alignment
    __shared__ float w_s[32 * CI_CH * 12];     // 32 co x 8 ci x 9 (stride 12 -> float4-aligned)

    const int tid = threadIdx.x;
    const int qx  = tid & 3;            // 4-wide pixel group
    const int row = (tid >> 2) & 7;     // y within tile
    const int cog = tid >> 5;           // 0..7 -> co group of 4

    const int tx = blockIdx.x % tilesX;
    const int ty = blockIdx.x / tilesX;
    const int co_base = blockIdx.y * 32;
    const int n = blockIdx.z;

    const int x0 = tx * 16, y0 = ty * 8;
    const int x = x0 + qx * 4, y = y0 + row;

    const float* inN = in + (size_t)n * IN_CH * H * W;

    float acc[4][4];
    #pragma unroll
    for (int j = 0; j < 4; j++)
        #pragma unroll
        for (int p = 0; p < 4; p++) acc[j][p] = 0.f;

    for (int cc = 0; cc < IN_CH; cc += CI_CH) {
        // ---- stage input halo tile: 8 ci x 10 x 18 ----
        for (int idx = tid; idx < CI_CH * 10 * 18; idx += 256) {
            int ci  = idx / 180;
            int rem = idx - ci * 180;
            int r   = rem / 18;
            int c   = rem - r * 18;
            int gy = y0 + r - 1, gx = x0 + c - 1;
            float v = 0.f;
            if ((unsigned)gy < (unsigned)H && (unsigned)gx < (unsigned)W)
                v = inN[((size_t)(cc + ci) * H + gy) * W + gx];
            in_s[ci][r][c] = v;
        }
        // ---- stage weights: 32 co x 8 ci x 9 ----
        for (int idx = tid; idx < 32 * CI_CH * 9; idx += 256) {
            int co  = idx / 72;
            int rem = idx - co * 72;
            int ci  = rem / 9;
            int k   = rem - ci * 9;
            w_s[(co * CI_CH + ci) * 12 + k] =
                wgt[((size_t)(co_base + co) * IN_CH + cc + ci) * 9 + k];
        }
        __syncthreads();

        #pragma unroll
        for (int ci = 0; ci < CI_CH; ci++) {
            // preload this thread's 4 co x 9 weights into registers
            float wreg[4][9];
            #pragma unroll
            for (int j = 0; j < 4; j++) {
                const float* wp = &w_s[((cog * 4 + j) * CI_CH + ci) * 12];
                float4 w0 = *(const float4*)wp;
                float4 w1 = *(const float4*)(wp + 4);
                wreg[j][0] = w0.x; wreg[j][1] = w0.y; wreg[j][2] = w0.z; wreg[j][3] = w0.w;
                wreg[j][4] = w1.x; wreg[j][5] = w1.y; wreg[j][6] = w1.z; wreg[j][7] = w1.w;
                wreg[j][8] = wp[8];
            }
            #pragma unroll
            for (int kh = 0; kh < 3; kh++) {
                const float* ip = &in_s[ci][row + kh][qx * 4];
                float4 i0 = *(const float4*)ip;
                float2 i1 = *(const float2*)(ip + 4);
                float iv[6] = {i0.x, i0.y, i0.z, i0.w, i1.x, i1.y};
                #pragma unroll
                for (int kw = 0; kw < 3; kw++)
                    #pragma unroll
                    for (int j = 0; j < 4; j++)
                        #pragma unroll
                        for (int p = 0; p < 4; p++)
                            acc[j][p] = fmaf(iv[kw + p], wreg[j][kh * 3 + kw], acc[j][p]);
            }
        }
        __syncthreads();
    }

    if (x < W) {   // only W=8 level has partial tiles; H always divides 8
        #pragma unroll
        for (int j = 0; j < 4; j++) {
            int co = co_base + cog * 4 + j;
            float sc = scale[co], bi = bias[co];
            float4 o;
            o.x = fmaxf(fmaf(acc[j][0], sc, bi), 0.f);
            o.y = fmaxf(fmaf(acc[j][1], sc, bi), 0.f);
            o.z = fmaxf(fmaf(acc[j][2], sc, bi), 0.f);
            o.w = fmaxf(fmaf(acc[j][3], sc, bi), 0.f);
            *(float4*)&out[((size_t)(n * IN_CH + co) * H + y) * W + x] = o;
        }
    }
}

// ---------------------------------------------------------------------------
// 1x1 conv, 256 -> 80 channels, + bias (cls head final).
// Block: 256 threads, 64 pixels, all 80 co. Thread: 5 co x 4 px.
// ---------------------------------------------------------------------------
__global__ __launch_bounds__(256) void conv1x1_cls(
    const float* __restrict__ a, const float* __restrict__ wf,
    const float* __restrict__ bf, float* __restrict__ out, int HW)
{
    __shared__ float a_s[64][64];
    __shared__ float w_s[80][65];

    const int tid = threadIdx.x;
    const int pxg = tid & 15;       // x4 pixels
    const int cg  = tid >> 4;       // 0..15 -> co = cg*5 + j
    const int p0  = blockIdx.x * 64;
    const int n   = blockIdx.y;
    const float* aN = a + (size_t)n * IN_CH * HW;

    float acc[5][4];
    #pragma unroll
    for (int j = 0; j < 5; j++)
        #pragma unroll
        for (int p = 0; p < 4; p++) acc[j][p] = 0.f;

    for (int cc = 0; cc < IN_CH; cc += 64) {
        for (int idx = tid; idx < 64 * 64; idx += 256) {
            int ci = idx >> 6, px = idx & 63;
            a_s[ci][px] = aN[(size_t)(cc + ci) * HW + p0 + px];
        }
        for (int idx = tid; idx < 80 * 64; idx += 256) {
            int co = idx >> 6, ci = idx & 63;
            w_s[co][ci] = wf[co * IN_CH + cc + ci];
        }
        __syncthreads();

        #pragma unroll 8
        for (int ci = 0; ci < 64; ci++) {
            float4 av = *(const float4*)&a_s[ci][pxg * 4];
            #pragma unroll
            for (int j = 0; j < 5; j++) {
                float wv = w_s[cg * 5 + j][ci];
                acc[j][0] = fmaf(av.x, wv, acc[j][0]);
                acc[j][1] = fmaf(av.y, wv, acc[j][1]);
                acc[j][2] = fmaf(av.z, wv, acc[j][2]);
                acc[j][3] = fmaf(av.w, wv, acc[j][3]);
            }
        }
        __syncthreads();
    }

    #pragma unroll
    for (int j = 0; j < 5; j++) {
        int co = cg * 5 + j;
        float bv = bf[co];
        float4 o = {acc[j][0] + bv, acc[j][1] + bv, acc[j][2] + bv, acc[j][3] + bv};
        *(float4*)&out[((size_t)n * 80 + co) * HW + p0 + pxg * 4] = o;
    }
}

// ---------------------------------------------------------------------------
// 1x1 conv, 256 -> 5 channels, + bias; ch0 -> centerness, ch1..4 -> max(raw*stride,0)
// Thread: 4 consecutive pixels, all 5 channels.
// ---------------------------------------------------------------------------
__global__ __launch_bounds__(256) void conv1x1_reg(
    const float* __restrict__ a, const float* __restrict__ wf,
    const float* __restrict__ bf, float* __restrict__ out_reg,
    float* __restrict__ out_cent, int HW, float strideF)
{
    __shared__ float w_s[5 * IN_CH];
    const int tid = threadIdx.x;
    for (int idx = tid; idx < 5 * IN_CH; idx += 256) w_s[idx] = wf[idx];
    __syncthreads();

    const int n  = blockIdx.y;
    const int px = (blockIdx.x * 256 + tid) * 4;
    if (px >= HW) return;

    const float* aN = a + (size_t)n * IN_CH * HW + px;
    float acc[5][4];
    #pragma unroll
    for (int j = 0; j < 5; j++)
        #pragma unroll
        for (int p = 0; p < 4; p++) acc[j][p] = 0.f;

    #pragma unroll 4
    for (int ci = 0; ci < IN_CH; ci++) {
        float4 av = *(const float4*)&aN[(size_t)ci * HW];
        #pragma unroll
        for (int j = 0; j < 5; j++) {
            float wv = w_s[j * IN_CH + ci];
            acc[j][0] = fmaf(av.x, wv, acc[j][0]);
            acc[j][1] = fmaf(av.y, wv, acc[j][1]);
            acc[j][2] = fmaf(av.z, wv, acc[j][2]);
            acc[j][3] = fmaf(av.w, wv, acc[j][3]);
        }
    }

    // centerness = raw ch0
    {
        float bv = bf[0];
        float4 o = {acc[0][0] + bv, acc[0][1] + bv, acc[0][2] + bv, acc[0][3] + bv};
        *(float4*)&out_cent[(size_t)n * HW + px] = o;
    }
    // reg chans: max(raw * stride, 0)
    #pragma unroll
    for (int j = 1; j < 5; j++) {
        float bv = bf[j];
        float4 o;
        o.x = fmaxf((acc[j][0] + bv) * strideF, 0.f);
        o.y = fmaxf((acc[j][1] + bv) * strideF, 0.f);
        o.z = fmaxf((acc[j][2] + bv) * strideF, 0.f);
        o.w = fmaxf((acc[j][3] + bv) * strideF, 0.f);
        *(float4*)&out_reg[((size_t)n * 4 + (j - 1)) * HW + px] = o;
    }
}

// ---------------------------------------------------------------------------
extern "C" void kernel_launch(void* const* d_in, const int* in_sizes, int n_in,
                              void* d_out, int out_size, void* d_ws, size_t ws_size,
                              hipStream_t stream)
{
    static const int   SZH[5]     = {128, 64, 32, 16, 8};
    static const float STRIDES[5] = {8.f, 16.f, 32.f, 64.f, 128.f};
    static const size_t SPREF[5]  = {0, 16384, 20480, 21504, 21760}; // prefix of H*W

    const float* fpn[5];
    for (int i = 0; i < 5; i++) fpn[i] = (const float*)d_in[i];
    const float* cls_w  = (const float*)d_in[5];
    const float* cls_s  = (const float*)d_in[6];
    const float* cls_b  = (const float*)d_in[7];
    const float* cls_fw = (const float*)d_in[8];
    const float* cls_fb = (const float*)d_in[9];
    const float* reg_w  = (const float*)d_in[10];
    const float* reg_s  = (const float*)d_in[11];
    const float* reg_b  = (const float*)d_in[12];
    const float* reg_fw = (const float*)d_in[13];
    const float* reg_fb = (const float*)d_in[14];

    float* out = (float*)d_out;

    const size_t BUF_ELTS = (size_t)4 * 256 * 128 * 128;
    float *buf0, *buf1;
    if (ws_size >= 2 * BUF_ELTS * sizeof(float)) {
        buf0 = (float*)d_ws;
        buf1 = (float*)((char*)d_ws + BUF_ELTS * sizeof(float));
    } else {
        hipGetSymbolAddress((void**)&buf0, HIP_SYMBOL(g_buf0));
        hipGetSymbolAddress((void**)&buf1, HIP_SYMBOL(g_buf1));
    }

    const size_t regBase  = 320ul * 21824;            // after all cls outputs
    const size_t centBase = regBase + 16ul * 21824;   // after all reg outputs

    for (int l = 0; l < 5; l++) {
        const int H = SZH[l], W = SZH[l], HW = H * W;
        const int tilesX = (W + 15) / 16;
        const int tilesY = (H + 7) / 8;
        dim3 cgrid(tilesX * tilesY, IN_CH / 32, 4);

        for (int head = 0; head < 2; head++) {
            const float* cw = head == 0 ? cls_w : reg_w;
            const float* cs = head == 0 ? cls_s : reg_s;
            const float* cb = head == 0 ? cls_b : reg_b;

            const float* src = fpn[l];
            float* dst = buf0;
            for (int i = 0; i < 4; i++) {
                conv3x3_bn_relu<<<cgrid, 256, 0, stream>>>(
                    src, cw + (size_t)i * IN_CH * IN_CH * 9,
                    cs + i * IN_CH, cb + i * IN_CH, dst, H, W, tilesX);
                src = dst;
                dst = (dst == buf0) ? buf1 : buf0;
            }

            if (head == 0) {
                dim3 g(HW / 64, 4);
                conv1x1_cls<<<g, 256, 0, stream>>>(
                    src, cls_fw, cls_fb, out + 320ul * SPREF[l], HW);
            } else {
                dim3 g((HW + 1023) / 1024, 4);
                conv1x1_reg<<<g, 256, 0, stream>>>(
                    src, reg_fw, reg_fb,
                    out + regBase + 16ul * SPREF[l],
                    out + centBase + 4ul * SPREF[l],
                    HW, STRIDES[l]);
            }
        }
    }
}

// Round 2
// 2649.058 us; speedup vs baseline: 7.4980x; 7.4980x over previous
//
#include <hip/hip_runtime.h>

typedef __attribute__((ext_vector_type(8))) short short8;
typedef __attribute__((ext_vector_type(4))) float f32x4;

#define ACT_ELEMS 22347776ul   /* 4 * 21824 * 256 */
#define WSTEP     589824       /* 9 * 256 * 256 */

__device__ unsigned short g_actC[ACT_ELEMS];
__device__ unsigned short g_actA0[ACT_ELEMS];
__device__ unsigned short g_actB0[ACT_ELEMS];
__device__ unsigned short g_actA1[ACT_ELEMS];
__device__ unsigned short g_actB1[ACT_ELEMS];
__device__ unsigned short g_wc[4 * WSTEP];
__device__ unsigned short g_wr[4 * WSTEP];
__device__ unsigned short g_w1c[80 * 256];

// per-level constants: W(=H), log2(C), R, log2(tilesX), numTiles, HW, act offset,
// reciprocal for div by (C+2), output bases, stride scale
__constant__ int      C_W[5]    = {128, 64, 32, 16, 8};
__constant__ int      C_LC[5]   = {5, 5, 5, 4, 3};
__constant__ int      C_R[5]    = {8, 8, 8, 16, 32};
__constant__ int      C_LTX[5]  = {2, 1, 0, 0, 0};
__constant__ int      C_NT[5]   = {64, 16, 4, 1, 1};
__constant__ int      C_HW[5]   = {16384, 4096, 1024, 256, 64};
__constant__ unsigned C_LOFF[5] = {0u, 16777216u, 20971520u, 22020096u, 22282240u};
__constant__ unsigned C_RCP[5]  = {123363u, 123363u, 123363u, 233017u, 419431u};
__constant__ unsigned C_CLSO[5] = {0u, 5242880u, 6553600u, 6881280u, 6963200u};
__constant__ unsigned C_REGO[5] = {6983680u, 7245824u, 7311360u, 7327744u, 7331840u};
__constant__ unsigned C_CENTO[5]= {7332864u, 7398400u, 7414784u, 7418880u, 7419904u};
__constant__ float    C_STRF[5] = {8.f, 16.f, 32.f, 64.f, 128.f};

static __device__ __forceinline__ unsigned short f2bf(float f) {
    unsigned u = __float_as_uint(f);
    unsigned r = (u + 0x7FFFu + ((u >> 16) & 1u)) >> 16;
    return (unsigned short)r;
}
static __device__ __forceinline__ float bf2f(unsigned short b) {
    return __uint_as_float(((unsigned)b) << 16);
}

// ---------------------------------------------------------------------------
// weight convert: (4,256,256,3,3) fp32 -> [step*9+tap][co][ci] bf16
// grid: (256 co, 36 step*tap, 2 head), block 256 = ci
// ---------------------------------------------------------------------------
__global__ __launch_bounds__(256) void cvt_w3(
    const float* __restrict__ wc, const float* __restrict__ wr,
    unsigned short* __restrict__ oc, unsigned short* __restrict__ orr)
{
    const int co = blockIdx.x, sm = blockIdx.y, head = blockIdx.z;
    const int step = sm / 9, tap = sm - step * 9;
    const int ci = threadIdx.x;
    const float* w = head ? wr : wc;
    unsigned short* o = head ? orr : oc;
    o[((size_t)sm * 256 + co) * 256 + ci] =
        f2bf(w[(((size_t)step * 256 + co) * 256 + ci) * 9 + tap]);
}

// 1x1 cls weight convert: (80,256) fp32 -> bf16
__global__ __launch_bounds__(256) void cvt_w1(
    const float* __restrict__ w, unsigned short* __restrict__ o)
{
    for (int idx = threadIdx.x; idx < 80 * 256; idx += 256)
        o[idx] = f2bf(w[idx]);
}

// ---------------------------------------------------------------------------
// input convert: fp32 NCHW -> bf16 NHWC.  grid: (256 px-tiles, 5 lvl, 4 n)
// ---------------------------------------------------------------------------
__global__ __launch_bounds__(256) void cvt_in(
    const float* __restrict__ f0, const float* __restrict__ f1,
    const float* __restrict__ f2, const float* __restrict__ f3,
    const float* __restrict__ f4, unsigned short* __restrict__ dstC)
{
    const int lvl = blockIdx.y, n = blockIdx.z;
    const int HW = C_HW[lvl];
    const int p0 = blockIdx.x * 64;
    if (p0 >= HW) return;
    const float* fp[5] = {f0, f1, f2, f3, f4};
    const float* src = fp[lvl] + (size_t)n * 256 * HW;
    unsigned short* dst = dstC + C_LOFF[lvl] + (size_t)n * HW * 256;
    const int tid = threadIdx.x;
    __shared__ float ts[64][65];

    for (int cc = 0; cc < 256; cc += 64) {
        for (int idx = tid; idx < 64 * 64; idx += 256) {
            int ci = idx >> 6, p = idx & 63;
            ts[ci][p] = src[(size_t)(cc + ci) * HW + p0 + p];
        }
        __syncthreads();
        for (int idx = tid; idx < 64 * 64; idx += 256) {
            int p = idx >> 6, ci = idx & 63;
            dst[(size_t)(p0 + p) * 256 + cc + ci] = f2bf(ts[ci][p]);
        }
        __syncthreads();
    }
}

// ---------------------------------------------------------------------------
// 3x3 conv + BN + ReLU, bf16 MFMA implicit GEMM.
// grid: (64 tiles, 5 levels, 8 = head*4 + n), block 512 = 8 waves.
// Block tile: 256 co x 256 px.  Wave: 64 co x 128 px (4 mf x 8 nf frags).
// ---------------------------------------------------------------------------
__global__ __launch_bounds__(512, 2) void conv3x3_mfma(
    const unsigned short* __restrict__ src0, const unsigned short* __restrict__ src1,
    unsigned short* __restrict__ dst0, unsigned short* __restrict__ dst1,
    const unsigned short* __restrict__ wt0, const unsigned short* __restrict__ wt1,
    const float* __restrict__ sc0, const float* __restrict__ bi0,
    const float* __restrict__ sc1, const float* __restrict__ bi1)
{
    const int lvl = blockIdx.y;
    const int tile = blockIdx.x;
    if (tile >= C_NT[lvl]) return;
    const int head = blockIdx.z >> 2, n = blockIdx.z & 3;

    const int W = C_W[lvl], H = W, lc = C_LC[lvl];
    const int Cc = 1 << lc, R = 256 >> lc;
    const int CP = Cc + 2;
    const int ltx = C_LTX[lvl];
    const int tx = tile & ((1 << ltx) - 1), ty = tile >> ltx;
    const int x0 = tx << lc, y0 = ty * R;

    const unsigned short* src = head ? src1 : src0;
    unsigned short*       dst = head ? dst1 : dst0;
    const unsigned short* wt  = head ? wt1 : wt0;
    const float* sc = head ? sc1 : sc0;
    const float* bi = head ? bi1 : bi0;
    const size_t actOff = (size_t)C_LOFF[lvl] + (size_t)n * ((size_t)H * W) * 256;
    src += actOff; dst += actOff;

    const int tid = threadIdx.x;
    const int lane = tid & 63, wid = tid >> 6;
    const int l16 = lane & 15, quad = lane >> 4;
    const int mh = wid & 3, wn = wid >> 2;

    __shared__ unsigned short bsh[13600];   // max (R+2)*(C+2) positions * 40 elems
    char* bb = (char*)bsh;

    int bpos[8], prow[8], pcol[8];
#pragma unroll
    for (int nf = 0; nf < 8; nf++) {
        int px = wn * 128 + nf * 16 + l16;
        int r = px >> lc, c = px & (Cc - 1);
        prow[nf] = r; pcol[nf] = c;
        bpos[nf] = (r * CP + c) * 80 + quad * 16;
    }

    f32x4 acc[4][8];
#pragma unroll
    for (int mf = 0; mf < 4; mf++)
#pragma unroll
        for (int nf = 0; nf < 8; nf++) acc[mf][nf] = (f32x4){0.f, 0.f, 0.f, 0.f};

    const int posCnt = (R + 2) * CP;
    const unsigned rcp = C_RCP[lvl];
    const int aOff = (mh * 64 + l16) * 256 + quad * 8;

    for (int cc = 0; cc < 256; cc += 32) {
        __syncthreads();
        // ---- stage B tile (with halo, zero-filled OOB) into LDS ----
        for (int idx = tid; idx < posCnt * 4; idx += 512) {
            int pos = idx >> 2, ch = idx & 3;
            int r = (int)(((unsigned)pos * rcp) >> 22);
            int c = pos - r * CP;
            int gy = y0 + r - 1, gx = x0 + c - 1;
            uint4 v; v.x = v.y = v.z = v.w = 0u;
            if ((unsigned)gy < (unsigned)H && (unsigned)gx < (unsigned)W)
                v = *(const uint4*)(src + (((gy * W + gx) << 8) + cc + ch * 8));
            *(uint4*)(bb + pos * 80 + ch * 16) = v;
        }
        __syncthreads();

#pragma unroll
        for (int kh = 0; kh < 3; kh++)
#pragma unroll
        for (int kw = 0; kw < 3; kw++) {
            const int tap = kh * 3 + kw;
            short8 af[4];
#pragma unroll
            for (int mf = 0; mf < 4; mf++)
                af[mf] = *(const short8*)(wt + (tap * 65536 + mf * 4096 + cc + aOff));
            const int toff = (kh * CP + kw) * 80;
#pragma unroll
            for (int nf = 0; nf < 8; nf++) {
                short8 bfr = *(const short8*)(bb + bpos[nf] + toff);
#pragma unroll
                for (int mf = 0; mf < 4; mf++)
                    acc[mf][nf] = __builtin_amdgcn_mfma_f32_16x16x32_bf16(
                        af[mf], bfr, acc[mf][nf], 0, 0, 0);
            }
        }
    }

    // ---- epilogue: BN + ReLU + cvt bf16, NHWC store ----
#pragma unroll
    for (int mf = 0; mf < 4; mf++) {
        const int co4 = mh * 64 + mf * 16 + quad * 4;
        const f32x4 s4 = *(const f32x4*)(sc + co4);
        const f32x4 b4 = *(const f32x4*)(bi + co4);
#pragma unroll
        for (int nf = 0; nf < 8; nf++) {
            int gy = y0 + prow[nf];
            if (gy < H) {
                int gx = x0 + pcol[nf];
                f32x4 v = acc[mf][nf];
                ushort4 o;
                o.x = f2bf(fmaxf(v[0] * s4[0] + b4[0], 0.f));
                o.y = f2bf(fmaxf(v[1] * s4[1] + b4[1], 0.f));
                o.z = f2bf(fmaxf(v[2] * s4[2] + b4[2], 0.f));
                o.w = f2bf(fmaxf(v[3] * s4[3] + b4[3], 0.f));
                *(ushort4*)(dst + ((gy * W + gx) * 256 + co4)) = o;
            }
        }
    }
}

// ---------------------------------------------------------------------------
// final 1x1 cls: 256 -> 80 + bias, MFMA, fp32 NCHW out.
// grid: (128 px-tiles, 5 lvl, 4 n), block 256 = 4 waves; wave: 80co x 32px.
// ---------------------------------------------------------------------------
__global__ __launch_bounds__(256) void final_cls(
    const unsigned short* __restrict__ act, const unsigned short* __restrict__ w,
    const float* __restrict__ bias, float* __restrict__ out)
{
    const int lvl = blockIdx.y, n = blockIdx.z;
    const int HW = C_HW[lvl];
    const int p0 = blockIdx.x * 128;
    if (p0 >= HW) return;

    const int tid = threadIdx.x;
    const int lane = tid & 63, wid = tid >> 6;
    const int l16 = lane & 15, quad = lane >> 4;

    const unsigned short* a = act + C_LOFF[lvl] + (size_t)n * HW * 256;

    int px[2], lpx[2];
#pragma unroll
    for (int j = 0; j < 2; j++) {
        px[j] = p0 + wid * 32 + j * 16 + l16;
        lpx[j] = px[j] < HW ? px[j] : 0;
    }

    f32x4 acc[5][2];
#pragma unroll
    for (int mf = 0; mf < 5; mf++) { acc[mf][0] = (f32x4){0,0,0,0}; acc[mf][1] = (f32x4){0,0,0,0}; }

    for (int cc = 0; cc < 256; cc += 32) {
        short8 b0 = *(const short8*)(a + (size_t)lpx[0] * 256 + cc + quad * 8);
        short8 b1 = *(const short8*)(a + (size_t)lpx[1] * 256 + cc + quad * 8);
#pragma unroll
        for (int mf = 0; mf < 5; mf++) {
            short8 av = *(const short8*)(w + (mf * 16 + l16) * 256 + cc + quad * 8);
            acc[mf][0] = __builtin_amdgcn_mfma_f32_16x16x32_bf16(av, b0, acc[mf][0], 0, 0, 0);
            acc[mf][1] = __builtin_amdgcn_mfma_f32_16x16x32_bf16(av, b1, acc[mf][1], 0, 0, 0);
        }
    }

    float* ob = out + C_CLSO[lvl] + (size_t)n * 80 * HW;
#pragma unroll
    for (int mf = 0; mf < 5; mf++) {
        const int co0 = mf * 16 + quad * 4;
#pragma unroll
        for (int j = 0; j < 2; j++) {
            if (px[j] < HW) {
#pragma unroll
                for (int r = 0; r < 4; r++)
                    ob[(size_t)(co0 + r) * HW + px[j]] = acc[mf][j][r] + bias[co0 + r];
            }
        }
    }
}

// ---------------------------------------------------------------------------
// final 1x1 reg: 256 -> 5 + bias; ch0 centerness, ch1..4 max(raw*stride,0).
// grid: (64 px-tiles, 5 lvl, 4 n), block 256, thread = 1 px.
// ---------------------------------------------------------------------------
__global__ __launch_bounds__(256) void final_reg(
    const unsigned short* __restrict__ act, const float* __restrict__ w,
    const float* __restrict__ bias, float* __restrict__ out)
{
    const int lvl = blockIdx.y, n = blockIdx.z;
    const int HW = C_HW[lvl];
    const int tid = threadIdx.x;

    __shared__ float ws[5 * 256];
    for (int idx = tid; idx < 5 * 256; idx += 256) ws[idx] = w[idx];
    __syncthreads();

    const int px = blockIdx.x * 256 + tid;
    if (px >= HW) return;

    const unsigned short* a = act + C_LOFF[lvl] + ((size_t)n * HW + px) * 256;
    float acc[5] = {0.f, 0.f, 0.f, 0.f, 0.f};

    for (int ci = 0; ci < 256; ci += 8) {
        ushort4 u0 = *(const ushort4*)(a + ci);
        ushort4 u1 = *(const ushort4*)(a + ci + 4);
        float xv[8] = {bf2f(u0.x), bf2f(u0.y), bf2f(u0.z), bf2f(u0.w),
                       bf2f(u1.x), bf2f(u1.y), bf2f(u1.z), bf2f(u1.w)};
#pragma unroll
        for (int j = 0; j < 5; j++) {
            const float* wj = &ws[j * 256 + ci];
#pragma unroll
            for (int k = 0; k < 8; k++) acc[j] = fmaf(xv[k], wj[k], acc[j]);
        }
    }

    const float strf = C_STRF[lvl];
    out[C_CENTO[lvl] + (size_t)n * HW + px] = acc[0] + bias[0];
    float* rb = out + C_REGO[lvl] + (size_t)n * 4 * HW;
#pragma unroll
    for (int j = 0; j < 4; j++)
        rb[(size_t)j * HW + px] = fmaxf((acc[j + 1] + bias[j + 1]) * strf, 0.f);
}

// ---------------------------------------------------------------------------
extern "C" void kernel_launch(void* const* d_in, const int* in_sizes, int n_in,
                              void* d_out, int out_size, void* d_ws, size_t ws_size,
                              hipStream_t stream)
{
    const float* cls_w  = (const float*)d_in[5];
    const float* cls_s  = (const float*)d_in[6];
    const float* cls_b  = (const float*)d_in[7];
    const float* cls_fw = (const float*)d_in[8];
    const float* cls_fb = (const float*)d_in[9];
    const float* reg_w  = (const float*)d_in[10];
    const float* reg_s  = (const float*)d_in[11];
    const float* reg_b  = (const float*)d_in[12];
    const float* reg_fw = (const float*)d_in[13];
    const float* reg_fb = (const float*)d_in[14];
    float* out = (float*)d_out;

    unsigned short *actC, *actA0, *actB0, *actA1, *actB1, *wc, *wr, *w1c;
    hipGetSymbolAddress((void**)&actC,  HIP_SYMBOL(g_actC));
    hipGetSymbolAddress((void**)&actA0, HIP_SYMBOL(g_actA0));
    hipGetSymbolAddress((void**)&actB0, HIP_SYMBOL(g_actB0));
    hipGetSymbolAddress((void**)&actA1, HIP_SYMBOL(g_actA1));
    hipGetSymbolAddress((void**)&actB1, HIP_SYMBOL(g_actB1));
    hipGetSymbolAddress((void**)&wc,    HIP_SYMBOL(g_wc));
    hipGetSymbolAddress((void**)&wr,    HIP_SYMBOL(g_wr));
    hipGetSymbolAddress((void**)&w1c,   HIP_SYMBOL(g_w1c));

    // weight + input conversion
    cvt_w3<<<dim3(256, 36, 2), 256, 0, stream>>>(cls_w, reg_w, wc, wr);
    cvt_w1<<<1, 256, 0, stream>>>(cls_fw, w1c);
    cvt_in<<<dim3(256, 5, 4), 256, 0, stream>>>(
        (const float*)d_in[0], (const float*)d_in[1], (const float*)d_in[2],
        (const float*)d_in[3], (const float*)d_in[4], actC);

    // 4 conv steps, both heads + all levels + all n batched per launch
    unsigned short* srcs[4][2] = {{actC, actC}, {actA0, actA1}, {actB0, actB1}, {actA0, actA1}};
    unsigned short* dsts[4][2] = {{actA0, actA1}, {actB0, actB1}, {actA0, actA1}, {actB0, actB1}};
    for (int s = 0; s < 4; s++) {
        conv3x3_mfma<<<dim3(64, 5, 8), 512, 0, stream>>>(
            srcs[s][0], srcs[s][1], dsts[s][0], dsts[s][1],
            wc + (size_t)s * WSTEP, wr + (size_t)s * WSTEP,
            cls_s + s * 256, cls_b + s * 256, reg_s + s * 256, reg_b + s * 256);
    }

    // finals
    final_cls<<<dim3(128, 5, 4), 256, 0, stream>>>(actB0, w1c, cls_fb, out);
    final_reg<<<dim3(64, 5, 4), 256, 0, stream>>>(actB1, reg_fw, reg_fb, out);
}

// Round 3
// 1254.268 us; speedup vs baseline: 15.8360x; 2.1120x over previous
//
#include <hip/hip_runtime.h>

typedef __attribute__((ext_vector_type(8))) short short8;
typedef __attribute__((ext_vector_type(4))) float f32x4;

#define ACT_ELEMS 22347776ul   /* 4 * 21824 * 256 */
#define WSTEP     589824       /* 9 * 32 * 256 * 8 */

__device__ unsigned short g_actC[ACT_ELEMS];
__device__ unsigned short g_actA0[ACT_ELEMS];
__device__ unsigned short g_actB0[ACT_ELEMS];
__device__ unsigned short g_actA1[ACT_ELEMS];
__device__ unsigned short g_actB1[ACT_ELEMS];
__device__ unsigned short g_wc[4 * WSTEP];
__device__ unsigned short g_wr[4 * WSTEP];
__device__ unsigned short g_w1c[80 * 256];

__constant__ int      C_W[5]    = {128, 64, 32, 16, 8};
__constant__ int      C_LXT[5]  = {4, 3, 2, 1, 0};          // log2(x-tiles)
__constant__ int      C_NT2[5]  = {256, 64, 16, 4, 2};      // tiles * 2 co-halves
__constant__ int      C_HW[5]   = {16384, 4096, 1024, 256, 64};
__constant__ unsigned C_LOFF[5] = {0u, 16777216u, 20971520u, 22020096u, 22282240u};
__constant__ unsigned C_CLSO[5] = {0u, 5242880u, 6553600u, 6881280u, 6963200u};
__constant__ unsigned C_REGO[5] = {6983680u, 7245824u, 7311360u, 7327744u, 7331840u};
__constant__ unsigned C_CENTO[5]= {7332864u, 7398400u, 7414784u, 7418880u, 7419904u};
__constant__ float    C_STRF[5] = {8.f, 16.f, 32.f, 64.f, 128.f};

static __device__ __forceinline__ unsigned short f2bf(float f) {
    unsigned u = __float_as_uint(f);
    unsigned r = (u + 0x7FFFu + ((u >> 16) & 1u)) >> 16;
    return (unsigned short)r;
}
static __device__ __forceinline__ float bf2f(unsigned short b) {
    return __uint_as_float(((unsigned)b) << 16);
}

// ---------------------------------------------------------------------------
// weight convert: (4,256,256,3,3) fp32 -> [step*9+tap][ci/8][co][ci%8] bf16
// (A-operand friendly: lane=co contiguous 16B rows)
// grid: (256 co, 36 step*tap, 2 head), block 256 = ci
// ---------------------------------------------------------------------------
__global__ __launch_bounds__(256) void cvt_w3(
    const float* __restrict__ wc, const float* __restrict__ wr,
    unsigned short* __restrict__ oc, unsigned short* __restrict__ orr)
{
    const int co = blockIdx.x, sm = blockIdx.y, head = blockIdx.z;
    const int step = sm / 9, tap = sm - step * 9;
    const int ci = threadIdx.x;
    const float* w = head ? wr : wc;
    unsigned short* o = head ? orr : oc;
    o[(((size_t)sm * 32 + (ci >> 3)) * 256 + co) * 8 + (ci & 7)] =
        f2bf(w[(((size_t)step * 256 + co) * 256 + ci) * 9 + tap]);
}

// 1x1 cls weight convert: (80,256) fp32 -> bf16
__global__ __launch_bounds__(256) void cvt_w1(
    const float* __restrict__ w, unsigned short* __restrict__ o)
{
    for (int idx = threadIdx.x; idx < 80 * 256; idx += 256)
        o[idx] = f2bf(w[idx]);
}

// ---------------------------------------------------------------------------
// input convert: fp32 NCHW -> bf16 NHWC.  grid: (256 px-tiles, 5 lvl, 4 n)
// ---------------------------------------------------------------------------
__global__ __launch_bounds__(256) void cvt_in(
    const float* __restrict__ f0, const float* __restrict__ f1,
    const float* __restrict__ f2, const float* __restrict__ f3,
    const float* __restrict__ f4, unsigned short* __restrict__ dstC)
{
    const int lvl = blockIdx.y, n = blockIdx.z;
    const int HW = C_HW[lvl];
    const int p0 = blockIdx.x * 64;
    if (p0 >= HW) return;
    const float* fp[5] = {f0, f1, f2, f3, f4};
    const float* src = fp[lvl] + (size_t)n * 256 * HW;
    unsigned short* dst = dstC + C_LOFF[lvl] + (size_t)n * HW * 256;
    const int tid = threadIdx.x;
    __shared__ float ts[64][65];

    for (int cc = 0; cc < 256; cc += 64) {
        for (int idx = tid; idx < 64 * 64; idx += 256) {
            int ci = idx >> 6, p = idx & 63;
            ts[ci][p] = src[(size_t)(cc + ci) * HW + p0 + p];
        }
        __syncthreads();
        for (int idx = tid; idx < 64 * 64; idx += 256) {
            int p = idx >> 6, ci = idx & 63;
            dst[(size_t)(p0 + p) * 256 + cc + ci] = f2bf(ts[ci][p]);
        }
        __syncthreads();
    }
}

// ---------------------------------------------------------------------------
// 3x3 conv + BN + ReLU, bf16 MFMA implicit GEMM, y-as-lane B layout.
// grid: (256 tile*cohalf, 5 lvl, 8 = head*4+n), block 256 = 4 waves.
// Block tile: 128 co x (16y x 8x) px.  Wave: 64 co x (16y x 4x) px.
// B frag = 16 y-rows at one x, one ci-32 group.  kw shift -> neighbor x frag,
// kh shift -> +1 y offset in LDS.  9 taps served by 3kh x 6x = 18 reads/k32.
// ---------------------------------------------------------------------------
__global__ __launch_bounds__(256, 3) void conv3x3_mfma(
    const unsigned short* __restrict__ src0, const unsigned short* __restrict__ src1,
    unsigned short* __restrict__ dst0, unsigned short* __restrict__ dst1,
    const unsigned short* __restrict__ wt0, const unsigned short* __restrict__ wt1,
    const float* __restrict__ sc0, const float* __restrict__ bi0,
    const float* __restrict__ sc1, const float* __restrict__ bi1)
{
    const int lvl = blockIdx.y;
    const int tc  = blockIdx.x;
    if (tc >= C_NT2[lvl]) return;
    const int head = blockIdx.z >> 2, n = blockIdx.z & 3;

    const int W = C_W[lvl], H = W;
    const int lxt = C_LXT[lvl];
    const int coh = tc & 1, tile = tc >> 1;
    const int tx = tile & ((1 << lxt) - 1), ty = tile >> lxt;
    const int x0 = tx * 8, y0 = ty * 16;

    const unsigned short* src = head ? src1 : src0;
    unsigned short*       dst = head ? dst1 : dst0;
    const unsigned short* wt  = head ? wt1 : wt0;
    const float* sc = head ? sc1 : sc0;
    const float* bi = head ? bi1 : bi0;
    const size_t actOff = (size_t)C_LOFF[lvl] + (size_t)n * ((size_t)H * W) * 256;
    src += actOff; dst += actOff;

    const int tid = threadIdx.x;
    const int lane = tid & 63, wid = tid >> 6;
    const int l16 = lane & 15, quad = lane >> 4;
    const int mh = wid & 1, wn = wid >> 1;

    const int cow = coh * 128 + mh * 64;   // wave co base
    const int x0w = x0 + wn * 4;           // wave x base (global)
    const int jw  = wn * 4;                // wave x base (LDS-local)

    // LDS: [g(8)][x(10, stride 11)][y(18)] x 8ci x 2B = 25344 B
    __shared__ unsigned short bsh[8 * 11 * 18 * 8];
    char* bb = (char*)bsh;

    f32x4 acc[4][4];
#pragma unroll
    for (int mf = 0; mf < 4; mf++)
#pragma unroll
        for (int nf = 0; nf < 4; nf++) acc[mf][nf] = (f32x4){0.f, 0.f, 0.f, 0.f};

    // lane-variant base offsets (bytes); all fragment reads use uniform adds
    const int ldsRB = (quad * 198 + l16) * 16;          // 198 = 11*18
    const char* aB  = (const char*)wt + (quad * 256 + l16) * 16;

    for (int cc = 0; cc < 256; cc += 64) {
        __syncthreads();
        // ---- stage 18y x 10x halo tile, 64 ci, zero-filled OOB ----
        for (int idx = tid; idx < 1440; idx += 256) {
            int g = idx & 7, pos = idx >> 3;
            int y = (pos * 205) >> 11;        // /10
            int x = pos - y * 10;
            int gy = y0 + y - 1, gx = x0 + x - 1;
            uint4 v; v.x = v.y = v.z = v.w = 0u;
            if ((unsigned)gy < (unsigned)H && (unsigned)gx < (unsigned)W)
                v = *(const uint4*)(src + (((gy * W + gx) << 8) + cc + g * 8));
            *(uint4*)(bb + ((g * 11 + x) * 18 + y) * 16) = v;
        }
        __syncthreads();

        const int cc8 = cc >> 3;
#pragma unroll
        for (int kk = 0; kk < 2; kk++) {
#pragma unroll
            for (int kh = 0; kh < 3; kh++) {
                short8 Bf[6];
#pragma unroll
                for (int j = 0; j < 6; j++)
                    Bf[j] = *(const short8*)(bb + ldsRB +
                                (kk * 792 + (jw + j) * 18 + kh) * 16);
#pragma unroll
                for (int kw = 0; kw < 3; kw++) {
                    const int tap = kh * 3 + kw;
                    short8 Af[4];
#pragma unroll
                    for (int mf = 0; mf < 4; mf++)
                        Af[mf] = *(const short8*)(aB +
                            (((tap * 32 + cc8 + kk * 4) * 256) + cow + mf * 16) * 16);
#pragma unroll
                    for (int nf = 0; nf < 4; nf++)
#pragma unroll
                        for (int mf = 0; mf < 4; mf++)
                            acc[mf][nf] = __builtin_amdgcn_mfma_f32_16x16x32_bf16(
                                Af[mf], Bf[nf + kw], acc[mf][nf], 0, 0, 0);
                }
            }
        }
    }

    // ---- epilogue: BN + ReLU + cvt bf16, NHWC store ----
    const int gy = y0 + l16;
    if (gy < H) {
#pragma unroll
        for (int mf = 0; mf < 4; mf++) {
            const int co4 = cow + mf * 16 + quad * 4;
            const f32x4 s4 = *(const f32x4*)(sc + co4);
            const f32x4 b4 = *(const f32x4*)(bi + co4);
#pragma unroll
            for (int nf = 0; nf < 4; nf++) {
                const int gx = x0w + nf;
                f32x4 v = acc[mf][nf];
                ushort4 o;
                o.x = f2bf(fmaxf(v[0] * s4[0] + b4[0], 0.f));
                o.y = f2bf(fmaxf(v[1] * s4[1] + b4[1], 0.f));
                o.z = f2bf(fmaxf(v[2] * s4[2] + b4[2], 0.f));
                o.w = f2bf(fmaxf(v[3] * s4[3] + b4[3], 0.f));
                *(ushort4*)(dst + ((gy * W + gx) * 256 + co4)) = o;
            }
        }
    }
}

// ---------------------------------------------------------------------------
// final 1x1 cls: 256 -> 80 + bias, MFMA, fp32 NCHW out.
// grid: (128 px-tiles, 5 lvl, 4 n), block 256 = 4 waves; wave: 80co x 32px.
// ---------------------------------------------------------------------------
__global__ __launch_bounds__(256) void final_cls(
    const unsigned short* __restrict__ act, const unsigned short* __restrict__ w,
    const float* __restrict__ bias, float* __restrict__ out)
{
    const int lvl = blockIdx.y, n = blockIdx.z;
    const int HW = C_HW[lvl];
    const int p0 = blockIdx.x * 128;
    if (p0 >= HW) return;

    const int tid = threadIdx.x;
    const int lane = tid & 63, wid = tid >> 6;
    const int l16 = lane & 15, quad = lane >> 4;

    const unsigned short* a = act + C_LOFF[lvl] + (size_t)n * HW * 256;

    int px[2], lpx[2];
#pragma unroll
    for (int j = 0; j < 2; j++) {
        px[j] = p0 + wid * 32 + j * 16 + l16;
        lpx[j] = px[j] < HW ? px[j] : 0;
    }

    f32x4 acc[5][2];
#pragma unroll
    for (int mf = 0; mf < 5; mf++) { acc[mf][0] = (f32x4){0,0,0,0}; acc[mf][1] = (f32x4){0,0,0,0}; }

    for (int cc = 0; cc < 256; cc += 32) {
        short8 b0 = *(const short8*)(a + (size_t)lpx[0] * 256 + cc + quad * 8);
        short8 b1 = *(const short8*)(a + (size_t)lpx[1] * 256 + cc + quad * 8);
#pragma unroll
        for (int mf = 0; mf < 5; mf++) {
            short8 av = *(const short8*)(w + (mf * 16 + l16) * 256 + cc + quad * 8);
            acc[mf][0] = __builtin_amdgcn_mfma_f32_16x16x32_bf16(av, b0, acc[mf][0], 0, 0, 0);
            acc[mf][1] = __builtin_amdgcn_mfma_f32_16x16x32_bf16(av, b1, acc[mf][1], 0, 0, 0);
        }
    }

    float* ob = out + C_CLSO[lvl] + (size_t)n * 80 * HW;
#pragma unroll
    for (int mf = 0; mf < 5; mf++) {
        const int co0 = mf * 16 + quad * 4;
#pragma unroll
        for (int j = 0; j < 2; j++) {
            if (px[j] < HW) {
#pragma unroll
                for (int r = 0; r < 4; r++)
                    ob[(size_t)(co0 + r) * HW + px[j]] = acc[mf][j][r] + bias[co0 + r];
            }
        }
    }
}

// ---------------------------------------------------------------------------
// final 1x1 reg: 256 -> 5 + bias; ch0 centerness, ch1..4 max(raw*stride,0).
// ---------------------------------------------------------------------------
__global__ __launch_bounds__(256) void final_reg(
    const unsigned short* __restrict__ act, const float* __restrict__ w,
    const float* __restrict__ bias, float* __restrict__ out)
{
    const int lvl = blockIdx.y, n = blockIdx.z;
    const int HW = C_HW[lvl];
    const int tid = threadIdx.x;

    __shared__ float ws[5 * 256];
    for (int idx = tid; idx < 5 * 256; idx += 256) ws[idx] = w[idx];
    __syncthreads();

    const int px = blockIdx.x * 256 + tid;
    if (px >= HW) return;

    const unsigned short* a = act + C_LOFF[lvl] + ((size_t)n * HW + px) * 256;
    float acc[5] = {0.f, 0.f, 0.f, 0.f, 0.f};

    for (int ci = 0; ci < 256; ci += 8) {
        ushort4 u0 = *(const ushort4*)(a + ci);
        ushort4 u1 = *(const ushort4*)(a + ci + 4);
        float xv[8] = {bf2f(u0.x), bf2f(u0.y), bf2f(u0.z), bf2f(u0.w),
                       bf2f(u1.x), bf2f(u1.y), bf2f(u1.z), bf2f(u1.w)};
#pragma unroll
        for (int j = 0; j < 5; j++) {
            const float* wj = &ws[j * 256 + ci];
#pragma unroll
            for (int k = 0; k < 8; k++) acc[j] = fmaf(xv[k], wj[k], acc[j]);
        }
    }

    const float strf = C_STRF[lvl];
    out[C_CENTO[lvl] + (size_t)n * HW + px] = acc[0] + bias[0];
    float* rb = out + C_REGO[lvl] + (size_t)n * 4 * HW;
#pragma unroll
    for (int j = 0; j < 4; j++)
        rb[(size_t)j * HW + px] = fmaxf((acc[j + 1] + bias[j + 1]) * strf, 0.f);
}

// ---------------------------------------------------------------------------
extern "C" void kernel_launch(void* const* d_in, const int* in_sizes, int n_in,
                              void* d_out, int out_size, void* d_ws, size_t ws_size,
                              hipStream_t stream)
{
    const float* cls_w  = (const float*)d_in[5];
    const float* cls_s  = (const float*)d_in[6];
    const float* cls_b  = (const float*)d_in[7];
    const float* cls_fw = (const float*)d_in[8];
    const float* cls_fb = (const float*)d_in[9];
    const float* reg_w  = (const float*)d_in[10];
    const float* reg_s  = (const float*)d_in[11];
    const float* reg_b  = (const float*)d_in[12];
    const float* reg_fw = (const float*)d_in[13];
    const float* reg_fb = (const float*)d_in[14];
    float* out = (float*)d_out;

    unsigned short *actC, *actA0, *actB0, *actA1, *actB1, *wc, *wr, *w1c;
    hipGetSymbolAddress((void**)&actC,  HIP_SYMBOL(g_actC));
    hipGetSymbolAddress((void**)&actA0, HIP_SYMBOL(g_actA0));
    hipGetSymbolAddress((void**)&actB0, HIP_SYMBOL(g_actB0));
    hipGetSymbolAddress((void**)&actA1, HIP_SYMBOL(g_actA1));
    hipGetSymbolAddress((void**)&actB1, HIP_SYMBOL(g_actB1));
    hipGetSymbolAddress((void**)&wc,    HIP_SYMBOL(g_wc));
    hipGetSymbolAddress((void**)&wr,    HIP_SYMBOL(g_wr));
    hipGetSymbolAddress((void**)&w1c,   HIP_SYMBOL(g_w1c));

    // weight + input conversion
    cvt_w3<<<dim3(256, 36, 2), 256, 0, stream>>>(cls_w, reg_w, wc, wr);
    cvt_w1<<<1, 256, 0, stream>>>(cls_fw, w1c);
    cvt_in<<<dim3(256, 5, 4), 256, 0, stream>>>(
        (const float*)d_in[0], (const float*)d_in[1], (const float*)d_in[2],
        (const float*)d_in[3], (const float*)d_in[4], actC);

    // 4 conv steps, both heads + all levels + all n batched per launch
    unsigned short* srcs[4][2] = {{actC, actC}, {actA0, actA1}, {actB0, actB1}, {actA0, actA1}};
    unsigned short* dsts[4][2] = {{actA0, actA1}, {actB0, actB1}, {actA0, actA1}, {actB0, actB1}};
    for (int s = 0; s < 4; s++) {
        conv3x3_mfma<<<dim3(256, 5, 8), 256, 0, stream>>>(
            srcs[s][0], srcs[s][1], dsts[s][0], dsts[s][1],
            wc + (size_t)s * WSTEP, wr + (size_t)s * WSTEP,
            cls_s + s * 256, cls_b + s * 256, reg_s + s * 256, reg_b + s * 256);
    }

    // finals
    final_cls<<<dim3(128, 5, 4), 256, 0, stream>>>(actB0, w1c, cls_fb, out);
    final_reg<<<dim3(64, 5, 4), 256, 0, stream>>>(actB1, reg_fw, reg_fb, out);
}